// Round 9
// baseline (94.155 us; speedup 1.0000x reference)
//
#include <hip/hip_runtime.h>

#define KERNEL_LEN 128
#define INPUT_LEN 1000000
#define PATH_NUM 10
#define L_TOTAL (INPUT_LEN + KERNEL_LEN)   // 1000128
#define BLOCK_SIZE 256
#define NWIN 977                            // ceil(L_TOTAL/1024)
#define WAVES_A (NWIN * 4)                  // 3908
#define NBUCKET 62                          // ii >> 14 -> 0..61
#define BSHIFT 14
#define SLICE (1 << BSHIFT)                 // 16384 floats = 64KB LDS slice
#define CAP 96                              // recs per (wave,bucket); mean 42, 8.4 sigma
#define NREGION (WAVES_A * NBUCKET)         // 242296
#define SPLIT 16
#define NBLK_B (NBUCKET * SPLIT)            // 992
#define OVF_CAP 4096

typedef int v4i __attribute__((ext_vector_type(4)));
typedef unsigned int u32;

// ---------------- Phase A: stream indices -> bucketed records (no gathers) --
__global__ __launch_bounds__(BLOCK_SIZE) void dtw_bucket(
    const int* __restrict__ path_k, const int* __restrict__ path_i,
    const int* __restrict__ path_length, const int* __restrict__ path_num,
    u32* __restrict__ counts, u32* __restrict__ recs,
    u32* __restrict__ ovfcnt, u32* __restrict__ ovf)
{
    __shared__ u32 lcnt[4][NBUCKET];
    __shared__ __align__(16) u32 stage[4][NBUCKET][32];   // ping-pong 2x16
    const int tid = threadIdx.x;
    for (int i = tid; i < 4 * NBUCKET; i += BLOCK_SIZE) ((u32*)lcnt)[i] = 0u;
    __syncthreads();

    const int wave = tid >> 6;
    const int lane = tid & 63;
    const int wg   = blockIdx.x * 4 + wave;
    const int n    = min(path_num[0], PATH_NUM);
    const int w0   = blockIdx.x * 1024;

    for (int p = 0; p < n; ++p) {
        const int len = path_length[p];
        if (w0 < len) {                                   // block-uniform
            const int t0 = w0 + tid * 4;
            const int tl = min(t0, L_TOTAL - 4);          // row-end clamp (masked lanes only)
            const v4i ik4 = *reinterpret_cast<const v4i*>(path_k + (size_t)p * L_TOTAL + tl);
            const v4i ii4 = *reinterpret_cast<const v4i*>(path_i + (size_t)p * L_TOTAL + tl);
            #pragma unroll
            for (int j = 0; j < 4; ++j) {
                if (t0 + j < len) {
                    const u32 ii  = (u32)ii4[j];
                    const u32 rec = ((u32)p << 27) | (ii << 7) | (u32)ik4[j];
                    const u32 b   = ii >> BSHIFT;
                    const u32 pos = atomicAdd(&lcnt[wave][b], 1u);
                    if (pos < CAP) {
                        stage[wave][b][pos & 31] = rec;
                        if ((pos & 15) == 15) {           // this lane flushes a full 16-block
                            const u32* s = &stage[wave][b][((pos >> 4) & 1) * 16];
                            const u32 gb = ((u32)wg * NBUCKET + b) * CAP + (pos & ~15u);
                            uint4 v0 = *(const uint4*)(s);
                            uint4 v1 = *(const uint4*)(s + 4);
                            uint4 v2 = *(const uint4*)(s + 8);
                            uint4 v3 = *(const uint4*)(s + 12);
                            *(uint4*)&recs[gb]      = v0;
                            *(uint4*)&recs[gb + 4]  = v1;
                            *(uint4*)&recs[gb + 8]  = v2;
                            *(uint4*)&recs[gb + 12] = v3;
                        }
                    } else {                              // ~never (P<1e-11); correctness net
                        const u32 op = atomicAdd(ovfcnt, 1u);
                        if (op < OVF_CAP) ovf[op] = rec;
                    }
                }
            }
        }
    }
    // tail flush: each lane owns one bucket of its wave (program order => LDS visible)
    if (lane < NBUCKET) {
        const u32 b  = (u32)lane;
        const u32 c  = lcnt[wave][b];
        const u32 cc = min(c, (u32)CAP);
        counts[(u32)wg * NBUCKET + b] = cc;
        const u32 base = ((u32)wg * NBUCKET + b) * CAP;
        for (u32 k = c & ~15u; k < cc; ++k)
            recs[base + k] = stage[wave][b][k & 31];
    }
}

// ---------------- Phase B: per-slice LDS gathers over the record lists ------
__global__ __launch_bounds__(BLOCK_SIZE) void dtw_gather(
    const float* __restrict__ kern, const float* __restrict__ x,
    const u32* __restrict__ counts, const u32* __restrict__ recs,
    float* __restrict__ partials)
{
    __shared__ float xs[SLICE];                           // 64KB slice
    __shared__ float ks[KERNEL_LEN];
    __shared__ float wsum[PATH_NUM][4];
    const int tid = threadIdx.x;
    const int b   = blockIdx.x;                           // 0..61
    const int s   = blockIdx.y;                           // 0..15
    if (tid < KERNEL_LEN) ks[tid] = kern[tid];
    const int base = b << BSHIFT;
    if (b < NBUCKET - 1) {                                // full slice: float4 copy
        const float4* xsrc = (const float4*)(x + base);
        float4* xdst = (float4*)xs;
        for (int i = tid; i < SLICE / 4; i += BLOCK_SIZE) xdst[i] = xsrc[i];
    } else {                                              // last slice: guarded
        for (int i = tid; i < SLICE; i += BLOCK_SIZE) {
            const int g = base + i;
            xs[i] = (g < INPUT_LEN) ? x[g] : 0.0f;
        }
    }
    __syncthreads();

    const int wave = tid >> 6;
    const int lane = tid & 63;
    float acc[PATH_NUM] = {};

    // regions of this bucket, strided over (s,wave); 1-deep (cnt,rec) prefetch
    int wg = s * 4 + wave;                                // 0..63
    u32 region = (u32)wg * NBUCKET + b;
    u32 cnt_c = counts[region];
    u32 rec_c = recs[region * CAP + lane];                // speculative (gated by cnt)
    while (wg < WAVES_A) {
        const u32 cnt  = cnt_c;
        const u32 rec0 = rec_c;
        const u32 gb   = region * CAP;
        const int wg2  = wg + 64;
        if (wg2 < WAVES_A) {                              // prefetch next region
            const u32 r2 = (u32)wg2 * NBUCKET + b;
            cnt_c = counts[r2];
            rec_c = recs[r2 * CAP + lane];
        }
        if ((u32)lane < cnt) {
            const u32 p  = rec0 >> 27;
            const u32 ii = (rec0 >> 7) & 0xFFFFFu;
            const float d = ks[rec0 & 127u] - xs[ii - base];
            const float sq = d * d;
            #pragma unroll
            for (int P = 0; P < PATH_NUM; ++P)
                acc[P] += (p == (u32)P) ? sq : 0.0f;
        }
        for (u32 st = 64; st < cnt; st += 64) {           // rare (cnt>64: ~0.02%)
            if (st + lane < cnt) {
                const u32 rec = recs[gb + st + lane];
                const u32 p  = rec >> 27;
                const u32 ii = (rec >> 7) & 0xFFFFFu;
                const float d = ks[rec & 127u] - xs[ii - base];
                const float sq = d * d;
                #pragma unroll
                for (int P = 0; P < PATH_NUM; ++P)
                    acc[P] += (p == (u32)P) ? sq : 0.0f;
            }
        }
        wg = wg2; region = (u32)wg * NBUCKET + b;
    }

    #pragma unroll
    for (int P = 0; P < PATH_NUM; ++P) {
        float v = acc[P];
        #pragma unroll
        for (int off = 32; off > 0; off >>= 1) v += __shfl_down(v, off, 64);
        if (lane == 0) wsum[P][wave] = v;
    }
    __syncthreads();
    if (tid < PATH_NUM) {
        const int blkid = s * NBUCKET + b;
        partials[(size_t)blkid * PATH_NUM + tid] =
            wsum[tid][0] + wsum[tid][1] + wsum[tid][2] + wsum[tid][3];
    }
}

// ---------------- Final reduce (+ overflow list) ----------------------------
__global__ __launch_bounds__(BLOCK_SIZE) void dtw_reduce(
    const float* __restrict__ kern, const float* __restrict__ x,
    const float* __restrict__ partials, const u32* __restrict__ ovfcnt,
    const u32* __restrict__ ovf, const int* __restrict__ path_num,
    float* __restrict__ out)
{
    const int tid = threadIdx.x;
    float acc[PATH_NUM] = {};
    for (int t = tid; t < NBLK_B; t += BLOCK_SIZE) {
        #pragma unroll
        for (int P = 0; P < PATH_NUM; ++P)
            acc[P] += partials[(size_t)t * PATH_NUM + P];
    }
    const u32 oc = min(*ovfcnt, (u32)OVF_CAP);
    for (u32 i = tid; i < oc; i += BLOCK_SIZE) {
        const u32 rec = ovf[i];
        const u32 p  = rec >> 27;
        const u32 ii = (rec >> 7) & 0xFFFFFu;
        const float d = kern[rec & 127u] - x[ii];
        const float sq = d * d;
        #pragma unroll
        for (int P = 0; P < PATH_NUM; ++P)
            acc[P] += (p == (u32)P) ? sq : 0.0f;
    }
    __shared__ float wsum[PATH_NUM][4];
    const int wave = tid >> 6, lane = tid & 63;
    #pragma unroll
    for (int P = 0; P < PATH_NUM; ++P) {
        float v = acc[P];
        #pragma unroll
        for (int off = 32; off > 0; off >>= 1) v += __shfl_down(v, off, 64);
        if (lane == 0) wsum[P][wave] = v;
    }
    __syncthreads();
    const int n = min(path_num[0], PATH_NUM);
    if (tid < PATH_NUM) {
        const float sv = wsum[tid][0] + wsum[tid][1] + wsum[tid][2] + wsum[tid][3];
        out[tid] = (tid < n) ? sv : 0.0f;                 // unconditional: no out-memset
    }
}

extern "C" void kernel_launch(void* const* d_in, const int* in_sizes, int n_in,
                              void* d_out, int out_size, void* d_ws, size_t ws_size,
                              hipStream_t stream) {
    const float* kern        = (const float*)d_in[0];
    const float* x           = (const float*)d_in[1];
    const int*   path_k      = (const int*)d_in[2];
    const int*   path_i      = (const int*)d_in[3];
    const int*   path_length = (const int*)d_in[4];
    const int*   path_num    = (const int*)d_in[5];
    float*       out         = (float*)d_out;

    // ws layout (u32 units): counts[NREGION] | ovfcnt | pad(7) | ovf[4096] | recs | partials
    u32* counts   = (u32*)d_ws;
    u32* ovfcnt   = counts + NREGION;                       // directly after counts
    u32* ovf      = counts + NREGION + 8;                   // 16B-aligned
    u32* recs     = counts + NREGION + 8 + OVF_CAP;         // 16B-aligned
    float* partials = (float*)(recs + (size_t)NREGION * CAP); // ~94MB total << ws

    // zero counts + ovfcnt every call (harness does not re-poison between replays)
    hipMemsetAsync(counts, 0, (size_t)(NREGION + 1) * sizeof(u32), stream);

    dtw_bucket<<<dim3(NWIN), dim3(BLOCK_SIZE), 0, stream>>>(
        path_k, path_i, path_length, path_num, counts, recs, ovfcnt, ovf);
    dtw_gather<<<dim3(NBUCKET, SPLIT), dim3(BLOCK_SIZE), 0, stream>>>(
        kern, x, counts, recs, partials);
    dtw_reduce<<<dim3(1), dim3(BLOCK_SIZE), 0, stream>>>(
        kern, x, partials, ovfcnt, ovf, path_num, out);
}